// Round 14
// baseline (786.973 us; speedup 1.0000x reference)
//
#include <hip/hip_runtime.h>
#include <stdint.h>

#define NB   32
#define NC   256
#define NPTS 4096
#define KCL  8
#define KC   384          // OpenBLAS sgemm KC panel
#define NPANEL 11         // 10*384 + 256
#define HALF0 192         // staged half size
#define BSTR  196         // buf row stride (floats)

// ---- numpy npyv AVX512 pairwise sum-of-squares (r6-verified bits) ----
__device__ float np_sumsq_avx512(const float* sh) {
  float half[2];
  #pragma unroll
  for (int h = 0; h < 2; ++h) {
    const float* ap = sh + h * 128;
    float rv[16];
    #pragma unroll
    for (int l = 0; l < 16; ++l) {
      float q[8];
      #pragma unroll
      for (int j = 0; j < 8; ++j) {
        float e = ap[16 * j + l];
        q[j] = __fmul_rn(e, e);
      }
      rv[l] = __fadd_rn(__fadd_rn(__fadd_rn(q[0], q[1]), __fadd_rn(q[2], q[3])),
                        __fadd_rn(__fadd_rn(q[4], q[5]), __fadd_rn(q[6], q[7])));
    }
    float t1[8];
    #pragma unroll
    for (int l = 0; l < 8; ++l) t1[l] = __fadd_rn(rv[l], rv[l + 8]);
    float t2[4];
    #pragma unroll
    for (int l = 0; l < 4; ++l) t2[l] = __fadd_rn(t1[l], t1[l + 2 + 2]);
    float t3[2];
    #pragma unroll
    for (int l = 0; l < 2; ++l) t3[l] = __fadd_rn(t2[l], t2[l + 2]);
    half[h] = __fadd_rn(t3[0], t3[1]);
  }
  return __fadd_rn(half[0], half[1]);
}

// same tree, elements at base[i*KCL + k] (centL is [c][k]) — r13-verified
__device__ float np_sumsq_avx512_s8(const float* base, int k) {
  float half[2];
  #pragma unroll
  for (int h = 0; h < 2; ++h) {
    float rv[16];
    #pragma unroll
    for (int l = 0; l < 16; ++l) {
      float q[8];
      #pragma unroll
      for (int j = 0; j < 8; ++j) {
        float e = base[(h * 128 + 16 * j + l) * KCL + k];
        q[j] = __fmul_rn(e, e);
      }
      rv[l] = __fadd_rn(__fadd_rn(__fadd_rn(q[0], q[1]), __fadd_rn(q[2], q[3])),
                        __fadd_rn(__fadd_rn(q[4], q[5]), __fadd_rn(q[6], q[7])));
    }
    float t1[8];
    #pragma unroll
    for (int l = 0; l < 8; ++l) t1[l] = __fadd_rn(rv[l], rv[l + 8]);
    float t2[4];
    #pragma unroll
    for (int l = 0; l < 4; ++l) t2[l] = __fadd_rn(t1[l], t1[l + 2 + 2]);
    float t3[2];
    #pragma unroll
    for (int l = 0; l < 2; ++l) t3[l] = __fadd_rn(t2[l], t2[l + 2]);
    half[h] = __fadd_rn(t3[0], t3[1]);
  }
  return __fadd_rn(half[0], half[1]);
}

// ---------------- init: centroids(cent0) = first 8 points ----------------
__global__ __launch_bounds__(256) void k_init(const float* __restrict__ X,
                                              float* __restrict__ cent0,
                                              float* __restrict__ cnorm0) {
  const int b = blockIdx.x >> 3, k = blockIdx.x & 7, c = threadIdx.x;
  __shared__ float sarr[NC];
  float v = X[(size_t)b * NC * NPTS + (size_t)c * NPTS + k];
  cent0[(b * NC + c) * KCL + k] = v;
  sarr[c] = v;
  __syncthreads();
  if (c == 0) cnorm0[b * KCL + k] = np_sumsq_avx512(sarr);
}

// ===== fused iteration: combine-prologue + assign + per-panel psum =====
// block = (b, panel), 384 threads. One pass over X per iteration.
__global__ __launch_bounds__(384) void k_iter(const float* __restrict__ X,
                                              const float* __restrict__ ppIn,
                                              const int* __restrict__ pcIn,
                                              float* __restrict__ ppOut,
                                              int* __restrict__ pcOut,
                                              const float* __restrict__ centPrev,
                                              float* __restrict__ centCur,
                                              const float* __restrict__ cnorm0,
                                              int it) {
  const int blk = blockIdx.x;
  const int b = blk / NPANEL, panel = blk % NPANEL;
  const int p0 = panel * KC;
  const int len = (panel < 10) ? KC : (NPTS - 10 * KC);   // 384 or 256
  const int t = threadIdx.x, lane = t & 63;

  __shared__ __align__(16) float centL[NC * KCL];   // 8 KB, [c][k]
  __shared__ float cnfL[KCL];
  __shared__ __align__(16) float buf[32 * BSTR];    // 25.1 KB
  __shared__ int perm[KC];
  __shared__ int wcnt[6][KCL], cbase[6][KCL], offs[KCL], hist[KCL];

  // ---- prologue: centroids for this iteration (r13-verified bits) ----
  if (it == 0) {
    if (t < 256) {
      const float4* cp = (const float4*)(centPrev + (size_t)b * NC * KCL);
      #pragma unroll
      for (int i2 = 0; i2 < 2; ++i2)
        ((float4*)centL)[i2 * 256 + t] = cp[i2 * 256 + t];
      if (t < KCL) cnfL[t] = cnorm0[b * KCL + t];
    }
  } else {
    if (t < 256) {
      const int c = t;
      #pragma unroll
      for (int k = 0; k < KCL; ++k) {
        float C = 0.f; int cnt = 0;
        for (int pnl = 0; pnl < NPANEL; ++pnl) {
          C = __fadd_rn(C, ppIn[(size_t)((b * NPANEL + pnl) * KCL + k) * NC + c]);
          cnt += pcIn[(b * NPANEL + pnl) * KCL + k];
        }
        const float mean = __fdiv_rn(C, (float)((cnt > 0) ? cnt : 1));
        const int ci = (b * NC + c) * KCL + k;
        float nv = (cnt > 0) ? mean : centPrev[ci];
        centCur[ci] = nv;               // duplicate identical writes: benign
        centL[c * KCL + k] = nv;
      }
    }
    __syncthreads();
    if (t < KCL) cnfL[t] = np_sumsq_avx512_s8(centL, t);
  }
  __syncthreads();

  // ---- phase 1: labels (r9-verified bits), thread = panel point ----
  int ml = -1;
  if (t < len) {
    float cnf[KCL];
    #pragma unroll
    for (int k = 0; k < KCL; ++k) cnf[k] = cnfL[k];
    const float* Xp = X + (size_t)b * NC * NPTS + p0 + t;
    const float4* cL4 = (const float4*)centL;
    float a = 0.f;
    float bb[KCL];
    #pragma unroll
    for (int k = 0; k < KCL; ++k) bb[k] = 0.f;
    #pragma unroll 8
    for (int c = 0; c < NC; ++c) {
      float x = Xp[(size_t)c * NPTS];    // lanes consecutive -> coalesced
      a = __fadd_rn(a, __fmul_rn(x, x));
      float4 c0 = cL4[c * 2], c1 = cL4[c * 2 + 1];
      bb[0] = __builtin_fmaf(x, c0.x, bb[0]);
      bb[1] = __builtin_fmaf(x, c0.y, bb[1]);
      bb[2] = __builtin_fmaf(x, c0.z, bb[2]);
      bb[3] = __builtin_fmaf(x, c0.w, bb[3]);
      bb[4] = __builtin_fmaf(x, c1.x, bb[4]);
      bb[5] = __builtin_fmaf(x, c1.y, bb[5]);
      bb[6] = __builtin_fmaf(x, c1.z, bb[6]);
      bb[7] = __builtin_fmaf(x, c1.w, bb[7]);
    }
    int lb = 0; float best = 3.4e38f;
    #pragma unroll
    for (int k = 0; k < KCL; ++k) {
      float d = __fadd_rn(__fsub_rn(a, __fmul_rn(2.0f, bb[k])), cnf[k]);
      if (d < best) { best = d; lb = k; }
    }
    ml = lb;
  }

  // ---- ballot counting sort (r11 pattern, 1 pt/thread, chunk = wave) ----
  const uint64_t lt = (1ull << lane) - 1ull;
  const int chunk = t >> 6;              // 0..5
  int rk = 0;
  #pragma unroll
  for (int kk = 0; kk < KCL; ++kk) {
    uint64_t m = __ballot(ml == kk);
    if (lane == 0) wcnt[chunk][kk] = (int)__popcll(m);
    if (ml == kk) rk = (int)__popcll(m & lt);
  }
  __syncthreads();
  if (t == 0) {
    int rr = 0;
    for (int kk = 0; kk < KCL; ++kk) {
      int s = 0;
      #pragma unroll
      for (int ch = 0; ch < 6; ++ch) { cbase[ch][kk] = rr + s; s += wcnt[ch][kk]; }
      offs[kk] = rr; hist[kk] = s; rr += s;
    }
  }
  __syncthreads();
  if (ml >= 0) perm[cbase[chunk][ml] + rk] = t;
  __syncthreads();

  // ---- phase 2: member-only chains per channel-group (r13-verified bits) ----
  const int k = t & 7, cl = t >> 3;      // valid for t < 256
  const int nf4 = (len - HALF0) >> 2;    // 48 or 16
  const float* Xb = X + (size_t)b * NC * NPTS + p0;

  for (int cg = 0; cg < 8; ++cg) {
    const float* Xs = Xb + (size_t)(cg * 32) * NPTS;
    // stage half0: 32ch x 192pt (L2/L3-hot: phase 1 just read it)
    #pragma unroll
    for (int i2 = 0; i2 < 4; ++i2) {
      int i = i2 * 384 + t;
      int c = i / 48, q4 = i - c * 48;
      *(float4*)&buf[c * BSTR + q4 * 4] =
          *(const float4*)(Xs + (size_t)c * NPTS + q4 * 4);
    }
    __syncthreads();
    float pa = 0.f;
    int base = 0, n = 0, nh0 = 0;
    if (t < 256) {
      base = offs[k]; n = hist[k]; nh0 = cbase[3][k] - offs[k];
      const float* bp = &buf[cl * BSTR];
      #pragma unroll 4
      for (int i = 0; i < nh0; ++i)
        pa = __fadd_rn(pa, bp[perm[base + i]]);
    }
    __syncthreads();
    // stage half1: remaining len-192 pts
    #pragma unroll
    for (int i2 = 0; i2 < 4; ++i2) {
      int i = i2 * 384 + t;
      int c = i / 48, q4 = i - c * 48;
      if (q4 < nf4)
        *(float4*)&buf[c * BSTR + q4 * 4] =
            *(const float4*)(Xs + (size_t)c * NPTS + HALF0 + q4 * 4);
    }
    __syncthreads();
    if (t < 256) {
      const float* bp = &buf[cl * BSTR];
      #pragma unroll 4
      for (int i = nh0; i < n; ++i)
        pa = __fadd_rn(pa, bp[perm[base + i] - HALF0]);
      ppOut[(size_t)((b * NPANEL + panel) * KCL + k) * NC + cg * 32 + cl] = pa;
      if (cl == 0 && cg == 0) pcOut[(b * NPANEL + panel) * KCL + k] = n;
    }
    __syncthreads();
  }
}

// ---------------- final output: fold panels -> means (r11 verbatim) ---------
__global__ __launch_bounds__(256) void k_out(const float* __restrict__ pp,
                                             const int* __restrict__ pc,
                                             float* __restrict__ out) {
  const int b = blockIdx.x >> 3, k = blockIdx.x & 7, c = threadIdx.x;
  float C = 0.f;
  int cnt = 0;
  for (int pnl = 0; pnl < NPANEL; ++pnl) {
    C = __fadd_rn(C, pp[(size_t)((b * NPANEL + pnl) * KCL + k) * NC + c]);
    cnt += pc[(b * NPANEL + pnl) * KCL + k];
  }
  out[(b * KCL + k) * NC + c] =
      (cnt > 0) ? __fdiv_rn(C, (float)cnt) : 0.0f;
}

extern "C" void kernel_launch(void* const* d_in, const int* in_sizes, int n_in,
                              void* d_out, int out_size, void* d_ws, size_t ws_size,
                              hipStream_t stream) {
  const float* X = (const float*)d_in[0];
  float* out = (float*)d_out;

  // ws: cent0 | cent1 | cnorm0 | pp0 | pp1 | pc0 | pc1   (~6.6 MB)
  float* cent0  = (float*)d_ws;
  float* cent1  = cent0 + (size_t)NB * NC * KCL;
  float* cnorm0 = cent1 + (size_t)NB * NC * KCL;
  float* pp0    = cnorm0 + NB * KCL;
  float* pp1    = pp0 + (size_t)NB * NPANEL * KCL * NC;
  int*   pc0    = (int*)(pp1 + (size_t)NB * NPANEL * KCL * NC);
  int*   pc1    = pc0 + (size_t)NB * NPANEL * KCL;

  float* ppB[2] = {pp0, pp1};
  int*   pcB[2] = {pc0, pc1};
  float* cent[2] = {cent0, cent1};

  k_init<<<NB * KCL, 256, 0, stream>>>(X, cent0, cnorm0);
  for (int it = 0; it <= 10; ++it) {
    float* prev = (it <= 1) ? cent0 : cent[(it - 1) & 1];
    float* cur  = (it == 0) ? cent1 : cent[it & 1];
    k_iter<<<NB * NPANEL, 384, 0, stream>>>(
        X, ppB[(it + 1) & 1], pcB[(it + 1) & 1],   // read prev parity
        ppB[it & 1], pcB[it & 1],                  // write cur parity
        prev, cur, cnorm0, it);
  }
  k_out<<<NB * KCL, 256, 0, stream>>>(ppB[0], pcB[0], out);   // it=10 -> parity 0
}

// Round 15
// 785.162 us; speedup vs baseline: 1.0023x; 1.0023x over previous
//
#include <hip/hip_runtime.h>
#include <stdint.h>

#define NB   32
#define NC   256
#define NPTS 4096
#define KCL  8
#define KC   384          // OpenBLAS sgemm KC panel
#define NPANEL 11         // 10*384 + 256
#define HALF0 192         // psum staged half size
#define BSTR  196         // psum buf row stride (floats)
#define ASTR  260         // assign chunk row stride (floats, 16B-mult, odd/4)

// ---- numpy npyv AVX512 pairwise sum-of-squares (r6-verified bits) ----
__device__ float np_sumsq_avx512(const float* sh) {
  float half[2];
  #pragma unroll
  for (int h = 0; h < 2; ++h) {
    const float* ap = sh + h * 128;
    float rv[16];
    #pragma unroll
    for (int l = 0; l < 16; ++l) {
      float q[8];
      #pragma unroll
      for (int j = 0; j < 8; ++j) {
        float e = ap[16 * j + l];
        q[j] = __fmul_rn(e, e);
      }
      rv[l] = __fadd_rn(__fadd_rn(__fadd_rn(q[0], q[1]), __fadd_rn(q[2], q[3])),
                        __fadd_rn(__fadd_rn(q[4], q[5]), __fadd_rn(q[6], q[7])));
    }
    float t1[8];
    #pragma unroll
    for (int l = 0; l < 8; ++l) t1[l] = __fadd_rn(rv[l], rv[l + 8]);
    float t2[4];
    #pragma unroll
    for (int l = 0; l < 4; ++l) t2[l] = __fadd_rn(t1[l], t1[l + 2 + 2]);
    float t3[2];
    #pragma unroll
    for (int l = 0; l < 2; ++l) t3[l] = __fadd_rn(t2[l], t2[l + 2]);
    half[h] = __fadd_rn(t3[0], t3[1]);
  }
  return __fadd_rn(half[0], half[1]);
}

// same tree, elements at base[i*KCL + k] (centL is [c][k]) — r13-verified
__device__ float np_sumsq_avx512_s8(const float* base, int k) {
  float half[2];
  #pragma unroll
  for (int h = 0; h < 2; ++h) {
    float rv[16];
    #pragma unroll
    for (int l = 0; l < 16; ++l) {
      float q[8];
      #pragma unroll
      for (int j = 0; j < 8; ++j) {
        float e = base[(h * 128 + 16 * j + l) * KCL + k];
        q[j] = __fmul_rn(e, e);
      }
      rv[l] = __fadd_rn(__fadd_rn(__fadd_rn(q[0], q[1]), __fadd_rn(q[2], q[3])),
                        __fadd_rn(__fadd_rn(q[4], q[5]), __fadd_rn(q[6], q[7])));
    }
    float t1[8];
    #pragma unroll
    for (int l = 0; l < 8; ++l) t1[l] = __fadd_rn(rv[l], rv[l + 8]);
    float t2[4];
    #pragma unroll
    for (int l = 0; l < 4; ++l) t2[l] = __fadd_rn(t1[l], t1[l + 2 + 2]);
    float t3[2];
    #pragma unroll
    for (int l = 0; l < 2; ++l) t3[l] = __fadd_rn(t2[l], t2[l + 2]);
    half[h] = __fadd_rn(t3[0], t3[1]);
  }
  return __fadd_rn(half[0], half[1]);
}

// ---------------- init: centroids(cent0) = first 8 points ----------------
__global__ __launch_bounds__(256) void k_init(const float* __restrict__ X,
                                              float* __restrict__ cent0,
                                              float* __restrict__ cnorm0) {
  const int b = blockIdx.x >> 3, k = blockIdx.x & 7, c = threadIdx.x;
  __shared__ float sarr[NC];
  float v = X[(size_t)b * NC * NPTS + (size_t)c * NPTS + k];
  cent0[(b * NC + c) * KCL + k] = v;
  sarr[c] = v;
  __syncthreads();
  if (c == 0) cnorm0[b * KCL + k] = np_sumsq_avx512(sarr);
}

// ---- assign: combine prologue (r13 bits) + chunked-LDS staged chains ----
__global__ __launch_bounds__(256) void k_assign(const float* __restrict__ X,
                                                const float* __restrict__ pp,
                                                const int* __restrict__ pc,
                                                const float* __restrict__ centPrev,
                                                float* __restrict__ centCur,
                                                const float* __restrict__ cnorm0,
                                                int* __restrict__ lab,
                                                int it) {
  const int blk = blockIdx.x;            // 512 = 32 b * 16 tiles
  const int b   = blk >> 4;
  const int n0  = (blk & 15) << 8;
  const int t   = threadIdx.x;

  __shared__ __align__(16) float centL[NC * KCL];   // 8 KB, [c][k]
  __shared__ float cnfL[KCL];
  __shared__ __align__(16) float xs[2][32 * ASTR];  // 2 x 32.5 KB dbuf

  if (it == 0) {
    const float4* cp = (const float4*)(centPrev + (size_t)b * NC * KCL);
    #pragma unroll
    for (int i2 = 0; i2 < 2; ++i2)
      ((float4*)centL)[i2 * 256 + t] = cp[i2 * 256 + t];
    if (t < KCL) cnfL[t] = cnorm0[b * KCL + t];
  } else {
    // inline combine: ordered panel fold (r13-verified bit pattern)
    const int c = t;
    #pragma unroll
    for (int k = 0; k < KCL; ++k) {
      float C = 0.f; int cnt = 0;
      for (int pnl = 0; pnl < NPANEL; ++pnl) {
        C = __fadd_rn(C, pp[(size_t)((b * NPANEL + pnl) * KCL + k) * NC + c]);
        cnt += pc[(b * NPANEL + pnl) * KCL + k];
      }
      const float mean = __fdiv_rn(C, (float)((cnt > 0) ? cnt : 1));
      const int ci = (b * NC + c) * KCL + k;
      float nv = (cnt > 0) ? mean : centPrev[ci];
      centCur[ci] = nv;                 // duplicate identical writes: benign
      centL[c * KCL + k] = nv;
    }
    __syncthreads();
    if (t < KCL) cnfL[t] = np_sumsq_avx512_s8(centL, t);
  }
  __syncthreads();

  const float* Xb = X + (size_t)b * NC * NPTS + n0;

  // stage chunk ch (32 channels x 256 pts) into xs[bi]: 8 float4 / thread
  #define ASTAGE(ch, bi)                                                   \
    _Pragma("unroll")                                                      \
    for (int i2 = 0; i2 < 8; ++i2) {                                       \
      int flat = i2 * 256 + t;                                             \
      int cc = flat >> 6, p4 = flat & 63;                                  \
      *(float4*)&xs[bi][cc * ASTR + p4 * 4] =                              \
          *(const float4*)(Xb + (size_t)((ch) * 32 + cc) * NPTS + p4 * 4); \
    }

  float cnf[KCL];
  #pragma unroll
  for (int k = 0; k < KCL; ++k) cnf[k] = cnfL[k];

  float a = 0.f;
  float bb[KCL];
  #pragma unroll
  for (int k = 0; k < KCL; ++k) bb[k] = 0.f;
  const float4* cL4 = (const float4*)centL;

  ASTAGE(0, 0);
  for (int ch = 0; ch < 8; ++ch) {
    __syncthreads();                    // xs[ch&1] ready
    if (ch < 7) ASTAGE(ch + 1, (ch + 1) & 1);
    const float* xp = &xs[ch & 1][t];
    const int c0 = ch * 32;
    #pragma unroll 8
    for (int cc = 0; cc < 32; ++cc) {
      float x = xp[cc * ASTR];          // lane-consecutive: conflict-free
      a = __fadd_rn(a, __fmul_rn(x, x));
      float4 c0v = cL4[(c0 + cc) * 2], c1v = cL4[(c0 + cc) * 2 + 1];
      bb[0] = __builtin_fmaf(x, c0v.x, bb[0]);
      bb[1] = __builtin_fmaf(x, c0v.y, bb[1]);
      bb[2] = __builtin_fmaf(x, c0v.z, bb[2]);
      bb[3] = __builtin_fmaf(x, c0v.w, bb[3]);
      bb[4] = __builtin_fmaf(x, c1v.x, bb[4]);
      bb[5] = __builtin_fmaf(x, c1v.y, bb[5]);
      bb[6] = __builtin_fmaf(x, c1v.z, bb[6]);
      bb[7] = __builtin_fmaf(x, c1v.w, bb[7]);
    }
    if (ch < 7) __syncthreads();        // chain reads done before next compute's stage check
  }

  int lb = 0; float best = 3.4e38f;
  #pragma unroll
  for (int k = 0; k < KCL; ++k) {
    float d = __fadd_rn(__fsub_rn(a, __fmul_rn(2.0f, bb[k])), cnf[k]);
    if (d < best) { best = d; lb = k; }
  }
  lab[b * NPTS + n0 + t] = lb;
  #undef ASTAGE
}

// ---- per-panel partials: half-staged buf, counting-sort + member chains ----
// (r13-verified bits throughout)
__global__ __launch_bounds__(256) void k_psum(const float* __restrict__ X,
                                              const int* __restrict__ lab,
                                              float* __restrict__ pp,
                                              int* __restrict__ pc) {
  const int blk = blockIdx.x;
  const int b = blk / 88, r = blk % 88, panel = r >> 3, cg = r & 7;
  const int p0 = panel * KC;
  const int len = (panel < 10) ? KC : (NPTS - 10 * KC);   // 384 or 256
  const int t = threadIdx.x, k = t & 7, cl = t >> 3, lane = t & 63;

  __shared__ __align__(16) float buf[32 * BSTR];   // 25.1 KB (192 pts/row)
  __shared__ int perm[KC];
  __shared__ int wcnt[6][KCL];
  __shared__ int cbase[6][KCL];
  __shared__ int offs[KCL], hist[KCL];

  const float* Xb = X + (size_t)b * NC * NPTS + (size_t)(cg * 32) * NPTS + p0;

  // ---- stage half0: 192 pts (always full) ----
  #pragma unroll
  for (int i2 = 0; i2 < 6; ++i2) {
    int i = i2 * 256 + t;
    int c = i / 48, q4 = i - c * 48;
    *(float4*)&buf[c * BSTR + q4 * 4] =
        *(const float4*)(Xb + (size_t)c * NPTS + q4 * 4);
  }

  // ---- ballot counting sort over full panel (labels only) ----
  const int* Lb = lab + b * NPTS + p0;
  const uint64_t lt = (1ull << lane) - 1ull;
  int ml0, ml1, rk0 = 0, rk1 = 0;
  {
    const int q = t;                 // chunks 0..3
    ml0 = (q < len) ? Lb[q] : -1;
    const int chunk = q >> 6;
    #pragma unroll
    for (int kk = 0; kk < KCL; ++kk) {
      uint64_t m = __ballot(ml0 == kk);
      if (lane == 0) wcnt[chunk][kk] = (int)__popcll(m);
      if (ml0 == kk) rk0 = (int)__popcll(m & lt);
    }
  }
  {
    const int q = 256 + t;           // chunks 4..7 (6,7 guarded)
    ml1 = (q < len) ? Lb[q] : -1;
    const int chunk = q >> 6;
    #pragma unroll
    for (int kk = 0; kk < KCL; ++kk) {
      uint64_t m = __ballot(ml1 == kk);
      if (lane == 0 && chunk < 6) wcnt[chunk][kk] = (int)__popcll(m);
      if (ml1 == kk) rk1 = (int)__popcll(m & lt);
    }
  }
  __syncthreads();
  if (t == 0) {
    int rr = 0;
    for (int kk = 0; kk < KCL; ++kk) {
      int s = 0;
      #pragma unroll
      for (int ch = 0; ch < 6; ++ch) { cbase[ch][kk] = rr + s; s += wcnt[ch][kk]; }
      offs[kk] = rr; hist[kk] = s; rr += s;
    }
  }
  __syncthreads();
  if (ml0 >= 0) perm[cbase[t >> 6][ml0] + rk0] = t;
  if (ml1 >= 0) perm[cbase[(256 + t) >> 6][ml1] + rk1] = 256 + t;
  __syncthreads();

  // ---- chain half0: members with p < 192 (chunks 0..2), ascending ----
  const int base = offs[k], n = hist[k];
  const int nh0 = cbase[3][k] - offs[k];
  const float* bp = &buf[cl * BSTR];
  float pa = 0.f;
  #pragma unroll 4
  for (int i = 0; i < nh0; ++i) {
    int p = perm[base + i];
    pa = __fadd_rn(pa, bp[p]);
  }
  __syncthreads();          // all chain-h0 reads done before overwrite

  // ---- stage half1: len-192 pts (192 or 64) ----
  const int nf4 = (len - HALF0) >> 2;         // 48 or 16
  #pragma unroll
  for (int i2 = 0; i2 < 6; ++i2) {
    int i = i2 * 256 + t;
    int c = i / 48, q4 = i - c * 48;
    if (q4 < nf4)
      *(float4*)&buf[c * BSTR + q4 * 4] =
          *(const float4*)(Xb + (size_t)c * NPTS + HALF0 + q4 * 4);
  }
  __syncthreads();

  // ---- chain half1: continue same pa, same ascending order ----
  #pragma unroll 4
  for (int i = nh0; i < n; ++i) {
    int p = perm[base + i] - HALF0;
    pa = __fadd_rn(pa, bp[p]);
  }
  pp[(size_t)((b * NPANEL + panel) * KCL + k) * NC + cg * 32 + cl] = pa;
  if (cl == 0) pc[(b * NPANEL + panel) * KCL + k] = n;
}

// ---------------- final output: fold panels -> means (r11 verbatim) ---------
__global__ __launch_bounds__(256) void k_out(const float* __restrict__ pp,
                                             const int* __restrict__ pc,
                                             float* __restrict__ out) {
  const int b = blockIdx.x >> 3, k = blockIdx.x & 7, c = threadIdx.x;
  float C = 0.f;
  int cnt = 0;
  for (int pnl = 0; pnl < NPANEL; ++pnl) {
    C = __fadd_rn(C, pp[(size_t)((b * NPANEL + pnl) * KCL + k) * NC + c]);
    cnt += pc[(b * NPANEL + pnl) * KCL + k];
  }
  out[(b * KCL + k) * NC + c] =
      (cnt > 0) ? __fdiv_rn(C, (float)cnt) : 0.0f;
}

extern "C" void kernel_launch(void* const* d_in, const int* in_sizes, int n_in,
                              void* d_out, int out_size, void* d_ws, size_t ws_size,
                              hipStream_t stream) {
  const float* X = (const float*)d_in[0];
  float* out = (float*)d_out;

  // ws: cent0 | cent1 | cnorm0 | lab | pp | pc    (~4.1 MB)
  float* cent0  = (float*)d_ws;
  float* cent1  = cent0 + (size_t)NB * NC * KCL;
  float* cnorm0 = cent1 + (size_t)NB * NC * KCL;
  int*   lab    = (int*)(cnorm0 + NB * KCL);
  float* pp     = (float*)(lab + (size_t)NB * NPTS);
  int*   pc     = (int*)(pp + (size_t)NB * NPANEL * KCL * NC);

  float* cent[2] = {cent0, cent1};

  k_init<<<NB * KCL, 256, 0, stream>>>(X, cent0, cnorm0);
  for (int it = 0; it <= 10; ++it) {
    float* prev = (it <= 1) ? cent0 : cent[(it - 1) & 1];
    float* cur  = (it == 0) ? cent1 : cent[it & 1];
    k_assign<<<NB * 16, 256, 0, stream>>>(X, pp, pc, prev, cur, cnorm0, lab, it);
    k_psum<<<NB * NPANEL * KCL, 256, 0, stream>>>(X, lab, pp, pc);
  }
  k_out<<<NB * KCL, 256, 0, stream>>>(pp, pc, out);
}